// Round 3
// baseline (4622.668 us; speedup 1.0000x reference)
//
#include <hip/hip_runtime.h>
#include <hip/hip_bf16.h>

#define T_ 2048
#define B_ 1024
#define H_ 256
#define I_ 8
#define A_ 8
#define DT_ 0.1f
#define EPS_ 1e-5f
#define LSTR 296  // bf16 elems per h_lds row (148 dwords: uniform 8/bank for b128 reads)
#define CH 64     // x-staging chunk (timesteps)

typedef __attribute__((ext_vector_type(8))) short bf16x8;
typedef __attribute__((ext_vector_type(4))) float f32x4;

#if __has_builtin(__builtin_amdgcn_cvt_pk_bf16_f32)
typedef __attribute__((ext_vector_type(2))) __bf16 bf16x2;
__device__ __forceinline__ int pk2bf(float a, float b) {
    bf16x2 r = __builtin_amdgcn_cvt_pk_bf16_f32(a, b);
    return __builtin_bit_cast(int, r);
}
#else
__device__ __forceinline__ short f2bf1(float f) {
    unsigned u = __builtin_bit_cast(unsigned, f);
    u += 0x7fffu + ((u >> 16) & 1u);   // RNE
    return (short)(u >> 16);
}
__device__ __forceinline__ int pk2bf(float a, float b) {
    return (int)(unsigned short)f2bf1(a) | ((int)f2bf1(b) << 16);
}
#endif

__launch_bounds__(512, 2)
__global__ void liquid_kernel(const float* __restrict__ x,
                              const float* __restrict__ W_in,
                              const float* __restrict__ b_in,
                              const float* __restrict__ tau_param,
                              const float* __restrict__ W_rec,
                              const float* __restrict__ g1,
                              const float* __restrict__ beta1,
                              const float* __restrict__ g2,
                              const float* __restrict__ beta2,
                              const float* __restrict__ head_w,
                              const float* __restrict__ head_b,
                              float* __restrict__ out) {
    __shared__ short  h_lds[16 * LSTR];         // h_t (bf16), cols 0..255 used
    __shared__ short  xstage[2][CH][16][8];     // x chunks (bf16), [buf][t][row][i]
    __shared__ alignas(16) int zero16[4];       // 16B of zeros for quads 1-3 ks=8 B-frag
    __shared__ float2 red[2][16];               // LN stat accumulators (double-buffered)
    __shared__ float2 redep[8][16];             // epilogue per-wave partials
    __shared__ float  hw[H_ * A_];              // head_w staging
    __shared__ float  outp[8][16][A_];          // epilogue head partials

    const int tid  = threadIdx.x;
    const int w    = tid >> 6;
    const int lane = tid & 63;
    const int quad = lane >> 4;
    const int l15  = lane & 15;   // batch-row within block
    const int r0   = blockIdx.x * 16;

    // ---- zero LDS state ----
    for (int i = tid; i < 16 * LSTR; i += 512) h_lds[i] = 0;
    if (tid < 4)  zero16[tid] = 0;
    if (tid < 64) ((float*)red)[tid] = 0.f;

    // ---- per-lane params for owned s-cols: c = w*32 + mt*16 + quad*4 + r ----
    float p_bin[8], p_g1s[8], p_b1s[8], p_decay[8];
#pragma unroll
    for (int mt = 0; mt < 2; ++mt)
#pragma unroll
        for (int r = 0; r < 4; ++r) {
            int c = w * 32 + mt * 16 + quad * 4 + r;
            int s = mt * 4 + r;
            p_bin[s] = b_in[c];
            p_g1s[s] = g1[c] * 2.885390082f;     // fold tanh's 2/ln2 scale
            p_b1s[s] = beta1[c] * 2.885390082f;
            float tp = tau_param[c];
            float sp = (tp > 20.f) ? tp : log1pf(expf(tp));  // softplus
            p_decay[s] = 1.0f - DT_ / sp;
        }

    // ---- A fragments resident in VGPRs: A[m=l15][k=quad*8+j] = W_ext[k][cA] ----
    // W_ext rows 0..255 = W_rec, 256..263 = W_in, 264..287 = 0
    bf16x8 afrag[2][9];
#pragma unroll
    for (int mt = 0; mt < 2; ++mt) {
        int cA = w * 32 + mt * 16 + l15;
#pragma unroll
        for (int ks = 0; ks < 9; ++ks) {
            bf16x8 f;
#pragma unroll
            for (int j = 0; j < 8; ++j) {
                int kg = ks * 32 + quad * 8 + j;
                float v;
                if (kg < 256)      v = W_rec[kg * H_ + cA];
                else if (kg < 264) v = W_in[(kg - 256) * H_ + cA];
                else               v = 0.f;
                f[j] = (short)pk2bf(v, v);
            }
            afrag[mt][ks] = f;
        }
    }

    // ---- x chunk loader: thread owns row=tid>>5, 4 float4 per chunk, coalesced ----
    const int xrow = tid >> 5, xl = tid & 31;
    const float* xrbase = x + (size_t)(r0 + xrow) * T_ * I_;
    float4 xr[4];

    // chunk 0: load + convert + store
#pragma unroll
    for (int j = 0; j < 4; ++j) xr[j] = ((const float4*)xrbase)[xl + 32 * j];
    {
#pragma unroll
        for (int j = 0; j < 4; ++j) {
            int e = j * 128 + xl * 4;          // element within chunk (t_local*8 + i)
            int tl = e >> 3, i0 = e & 7;       // i0 in {0,4}
            int2 pk = make_int2(pk2bf(xr[j].x, xr[j].y), pk2bf(xr[j].z, xr[j].w));
            *reinterpret_cast<int2*>(&xstage[0][tl][xrow][i0]) = pk;
        }
    }
    // issue chunk 1 loads (converted at t=32)
#pragma unroll
    for (int j = 0; j < 4; ++j) xr[j] = ((const float4*)(xrbase + (size_t)CH * I_))[xl + 32 * j];

    float hreg[8];
#pragma unroll
    for (int s = 0; s < 8; ++s) hreg[s] = 0.f;

    const short* hrow = &h_lds[l15 * LSTR + quad * 8];

    for (int t = 0; t < T_; ++t) {
        const int tc  = t & (CH - 1);
        const int c   = t >> 6;
        const int buf = c & 1;
        const int rb  = t & 1;

        __syncthreads();  // barrier #1: h_t, xstage, red-zero visible

        // zero the *other* stat buffer for next step (read of it finished before B1)
        if (w == 0 && quad == 0) red[rb ^ 1][l15] = make_float2(0.f, 0.f);

        if (tc == 32) {  // convert held regs (chunk c+1) into idle buffer
#pragma unroll
            for (int j = 0; j < 4; ++j) {
                int e = j * 128 + xl * 4;
                int tl = e >> 3, i0 = e & 7;
                int2 pk = make_int2(pk2bf(xr[j].x, xr[j].y), pk2bf(xr[j].z, xr[j].w));
                *reinterpret_cast<int2*>(&xstage[buf ^ 1][tl][xrow][i0]) = pk;
            }
        }
        if (tc == 34) {  // issue loads for chunk c+2 (vmcnt drain hits one barrier per chunk)
            int cc = c + 2; if (cc > (T_ / CH) - 1) cc = (T_ / CH) - 1;
            const float4* src = (const float4*)(xrbase + (size_t)cc * CH * I_);
#pragma unroll
            for (int j = 0; j < 4; ++j) xr[j] = src[xl + 32 * j];
        }

        // ---- GEMM: 4 independent MFMA chains (dep depth 5/4) ----
        const short* xb = (quad == 0) ? &xstage[buf][tc][l15][0] : (const short*)zero16;
        f32x4 a0a, a0b, a1a, a1b;
#pragma unroll
        for (int r = 0; r < 4; ++r) {
            a0a[r] = p_bin[r]; a1a[r] = p_bin[4 + r];
            a0b[r] = 0.f;      a1b[r] = 0.f;
        }
        bf16x8 b8 = *reinterpret_cast<const bf16x8*>(xb);
#pragma unroll
        for (int ks = 0; ks < 4; ++ks) {
            bf16x8 bA = *reinterpret_cast<const bf16x8*>(hrow + ks * 32);
            bf16x8 bB = *reinterpret_cast<const bf16x8*>(hrow + (ks + 4) * 32);
            a0a = __builtin_amdgcn_mfma_f32_16x16x32_bf16(afrag[0][ks],     bA, a0a, 0, 0, 0);
            a1a = __builtin_amdgcn_mfma_f32_16x16x32_bf16(afrag[1][ks],     bA, a1a, 0, 0, 0);
            a0b = __builtin_amdgcn_mfma_f32_16x16x32_bf16(afrag[0][ks + 4], bB, a0b, 0, 0, 0);
            a1b = __builtin_amdgcn_mfma_f32_16x16x32_bf16(afrag[1][ks + 4], bB, a1b, 0, 0, 0);
        }
        a0a = __builtin_amdgcn_mfma_f32_16x16x32_bf16(afrag[0][8], b8, a0a, 0, 0, 0);
        a1a = __builtin_amdgcn_mfma_f32_16x16x32_bf16(afrag[1][8], b8, a1a, 0, 0, 0);
        f32x4 acc0 = a0a + a0b, acc1 = a1a + a1b;

        // ---- LN partial: in-lane fold + 2 fire-and-forget LDS atomics ----
        float S  = ((acc0[0] + acc0[1]) + (acc0[2] + acc0[3]))
                 + ((acc1[0] + acc1[1]) + (acc1[2] + acc1[3]));
        float SQ = fmaf(acc0[0], acc0[0], fmaf(acc0[1], acc0[1],
                   fmaf(acc0[2], acc0[2], fmaf(acc0[3], acc0[3],
                   fmaf(acc1[0], acc1[0], fmaf(acc1[1], acc1[1],
                   fmaf(acc1[2], acc1[2], acc1[3] * acc1[3])))))));
        atomicAdd(&red[rb][l15].x, S);
        atomicAdd(&red[rb][l15].y, SQ);

        __syncthreads();  // barrier #2: stats complete, B-frag reads done

        float2 st = red[rb][l15];   // broadcast read (4 lanes/address)
        const float mu   = st.x * (1.f / 256.f);
        const float var  = fmaf(st.y, 1.f / 256.f, -mu * mu);
        const float rstd = __builtin_amdgcn_rsqf(var + EPS_);
        const float nmr  = -mu * rstd;

        // ---- f = tanh(LN*g1+b1); h = clamp(h*decay + DT*f) ----
#pragma unroll
        for (int s = 0; s < 8; ++s) {
            float v  = (s < 4) ? acc0[s] : acc1[s - 4];
            float tt = fmaf(v, rstd, nmr);
            float z2 = fmaf(tt, p_g1s[s], p_b1s[s]);            // 2z/ln2
            float e  = __builtin_amdgcn_exp2f(z2);              // e^(2z)
            float rc = __builtin_amdgcn_rcpf(e + 1.f);
            float fd = fmaf(rc, -2.f * DT_, DT_);               // DT*tanh(z)
            float h  = fmaf(hreg[s], p_decay[s], fd);
            hreg[s]  = fminf(10.f, fmaxf(-10.f, h));
        }
        int2 pk0 = make_int2(pk2bf(hreg[0], hreg[1]), pk2bf(hreg[2], hreg[3]));
        int2 pk1 = make_int2(pk2bf(hreg[4], hreg[5]), pk2bf(hreg[6], hreg[7]));
        *reinterpret_cast<int2*>(&h_lds[l15 * LSTR + w * 32 + quad * 4])      = pk0;
        *reinterpret_cast<int2*>(&h_lds[l15 * LSTR + w * 32 + 16 + quad * 4]) = pk1;
    }

    // ---- epilogue: out = LN(h_T; g2,b2) @ head_w + head_b ----
    for (int i = tid; i < H_ * A_; i += 512) hw[i] = head_w[i];
    __syncthreads();

    float S2 = 0.f, SQ2 = 0.f;
#pragma unroll
    for (int s = 0; s < 8; ++s) { S2 += hreg[s]; SQ2 = fmaf(hreg[s], hreg[s], SQ2); }
    S2 += __shfl_xor(S2, 16, 64);  SQ2 += __shfl_xor(SQ2, 16, 64);
    S2 += __shfl_xor(S2, 32, 64);  SQ2 += __shfl_xor(SQ2, 32, 64);
    if (quad == 0) redep[w][l15] = make_float2(S2, SQ2);
    __syncthreads();
    float2 rA = redep[quad][l15], rB = redep[quad + 4][l15];
    float St = rA.x + rB.x, SQt = rA.y + rB.y;
    St += __shfl_xor(St, 16, 64);  SQt += __shfl_xor(SQt, 16, 64);
    St += __shfl_xor(St, 32, 64);  SQt += __shfl_xor(SQt, 32, 64);
    const float mu   = St * (1.f / 256.f);
    const float var  = fmaf(SQt, 1.f / 256.f, -mu * mu);
    const float rstd = __builtin_amdgcn_rsqf(var + EPS_);

    float pa[8];
#pragma unroll
    for (int a = 0; a < 8; ++a) pa[a] = 0.f;
#pragma unroll
    for (int s = 0; s < 8; ++s) {
        int c = w * 32 + (s >> 2) * 16 + quad * 4 + (s & 3);
        float lnh = (hreg[s] - mu) * rstd * g2[c] + beta2[c];
        float4 w0 = *reinterpret_cast<const float4*>(&hw[c * 8]);
        float4 w1 = *reinterpret_cast<const float4*>(&hw[c * 8 + 4]);
        pa[0] += lnh * w0.x; pa[1] += lnh * w0.y; pa[2] += lnh * w0.z; pa[3] += lnh * w0.w;
        pa[4] += lnh * w1.x; pa[5] += lnh * w1.y; pa[6] += lnh * w1.z; pa[7] += lnh * w1.w;
    }
#pragma unroll
    for (int a = 0; a < 8; ++a) {
        pa[a] += __shfl_xor(pa[a], 16, 64);
        pa[a] += __shfl_xor(pa[a], 32, 64);
    }
    if (quad == 0) {
#pragma unroll
        for (int a = 0; a < 8; ++a) outp[w][l15][a] = pa[a];
    }
    __syncthreads();
    if (tid < 128) {
        int r = tid >> 3, a = tid & 7;
        float s = head_b[a];
#pragma unroll
        for (int ww = 0; ww < 8; ++ww) s += outp[ww][r][a];
        out[(size_t)(r0 + r) * A_ + a] = s;
    }
}

extern "C" void kernel_launch(void* const* d_in, const int* in_sizes, int n_in,
                              void* d_out, int out_size, void* d_ws, size_t ws_size,
                              hipStream_t stream) {
    const float* x         = (const float*)d_in[0];
    const float* W_in      = (const float*)d_in[1];
    const float* b_in      = (const float*)d_in[2];
    const float* tau_param = (const float*)d_in[3];
    const float* W_rec     = (const float*)d_in[4];
    const float* g1        = (const float*)d_in[5];
    const float* beta1     = (const float*)d_in[6];
    const float* g2        = (const float*)d_in[7];
    const float* beta2     = (const float*)d_in[8];
    const float* head_w    = (const float*)d_in[9];
    const float* head_b    = (const float*)d_in[10];
    float* out = (float*)d_out;

    liquid_kernel<<<64, 512, 0, stream>>>(x, W_in, b_in, tau_param, W_rec,
                                          g1, beta1, g2, beta2, head_w, head_b, out);
}

// Round 4
// 2474.964 us; speedup vs baseline: 1.8678x; 1.8678x over previous
//
#include <hip/hip_runtime.h>
#include <hip/hip_bf16.h>

#define T_ 2048
#define B_ 1024
#define H_ 256
#define I_ 8
#define A_ 8
#define DT_ 0.1f
#define EPS_ 1e-5f
#define LSTR 296  // bf16 elems per h_lds row
#define CH 64     // x-staging chunk (timesteps)

typedef __attribute__((ext_vector_type(8))) short bf16x8;
typedef __attribute__((ext_vector_type(4))) float f32x4;

#if __has_builtin(__builtin_amdgcn_cvt_pk_bf16_f32)
typedef __attribute__((ext_vector_type(2))) __bf16 bf16x2;
__device__ __forceinline__ int pk2bf(float a, float b) {
    bf16x2 r = __builtin_amdgcn_cvt_pk_bf16_f32(a, b);
    return __builtin_bit_cast(int, r);
}
#else
__device__ __forceinline__ short f2bf1(float f) {
    unsigned u = __builtin_bit_cast(unsigned, f);
    u += 0x7fffu + ((u >> 16) & 1u);   // RNE
    return (short)(u >> 16);
}
__device__ __forceinline__ int pk2bf(float a, float b) {
    return (int)(unsigned short)f2bf1(a) | ((int)f2bf1(b) << 16);
}
#endif

__launch_bounds__(512, 2)
__global__ void liquid_kernel(const float* __restrict__ x,
                              const float* __restrict__ W_in,
                              const float* __restrict__ b_in,
                              const float* __restrict__ tau_param,
                              const float* __restrict__ W_rec,
                              const float* __restrict__ g1,
                              const float* __restrict__ beta1,
                              const float* __restrict__ g2,
                              const float* __restrict__ beta2,
                              const float* __restrict__ head_w,
                              const float* __restrict__ head_b,
                              float* __restrict__ out) {
    __shared__ short  h_lds[16 * LSTR];          // h_t (bf16), cols 0..255 used
    __shared__ short  xstage[2][CH][16][8];      // x chunks (bf16), [buf][t][row][i]
    __shared__ alignas(16) int zero16[4];        // zero B-frag for quads 1-3 at ks=8
    __shared__ alignas(16) float2 redt[16][10];  // LN partials, TRANSPOSED [row][wave]+pad
    __shared__ float2 redep[8][16];              // epilogue partials
    __shared__ float  hw[H_ * A_];               // head_w staging
    __shared__ float  outp[8][16][A_];           // epilogue head partials

    const int tid  = threadIdx.x;
    const int w    = tid >> 6;
    const int lane = tid & 63;
    const int quad = lane >> 4;
    const int l15  = lane & 15;   // batch-row within block
    const int r0   = blockIdx.x * 16;

    // ---- zero LDS state ----
    for (int i = tid; i < 16 * LSTR; i += 512) h_lds[i] = 0;
    if (tid < 4) zero16[tid] = 0;

    // ---- per-lane params for owned s-cols: c = w*32 + mt*16 + quad*4 + r ----
    float p_bin[8], p_g1s[8], p_b1s[8], p_decay[8];
#pragma unroll
    for (int mt = 0; mt < 2; ++mt)
#pragma unroll
        for (int r = 0; r < 4; ++r) {
            int c = w * 32 + mt * 16 + quad * 4 + r;
            int s = mt * 4 + r;
            p_bin[s] = b_in[c];
            p_g1s[s] = g1[c] * 2.885390082f;     // fold tanh's 2/ln2 scale
            p_b1s[s] = beta1[c] * 2.885390082f;
            float tp = tau_param[c];
            float sp = (tp > 20.f) ? tp : log1pf(expf(tp));  // softplus
            p_decay[s] = 1.0f - DT_ / sp;
        }

    // ---- A fragments resident in VGPRs: A[m=l15][k=quad*8+j] = W_ext[k][cA] ----
    // W_ext rows 0..255 = W_rec, 256..263 = W_in, 264..287 = 0
    bf16x8 afrag[2][9];
#pragma unroll
    for (int mt = 0; mt < 2; ++mt) {
        int cA = w * 32 + mt * 16 + l15;
#pragma unroll
        for (int ks = 0; ks < 9; ++ks) {
            bf16x8 f;
#pragma unroll
            for (int j = 0; j < 8; ++j) {
                int kg = ks * 32 + quad * 8 + j;
                float v;
                if (kg < 256)      v = W_rec[kg * H_ + cA];
                else if (kg < 264) v = W_in[(kg - 256) * H_ + cA];
                else               v = 0.f;
                f[j] = (short)pk2bf(v, v);
            }
            afrag[mt][ks] = f;
        }
    }

    // ---- x chunk loader: thread owns row=tid>>5, 4 float4 per chunk, coalesced ----
    const int xrow = tid >> 5, xl = tid & 31;
    const float* xrbase = x + (size_t)(r0 + xrow) * T_ * I_;
    float4 xr[4];

    // chunk 0: load + convert + store (pre-loop, before first barrier)
#pragma unroll
    for (int j = 0; j < 4; ++j) xr[j] = ((const float4*)xrbase)[xl + 32 * j];
#pragma unroll
    for (int j = 0; j < 4; ++j) {
        int e = j * 128 + xl * 4;          // element within chunk (t_local*8 + i)
        int tl = e >> 3, i0 = e & 7;
        int2 pk = make_int2(pk2bf(xr[j].x, xr[j].y), pk2bf(xr[j].z, xr[j].w));
        *reinterpret_cast<int2*>(&xstage[0][tl][xrow][i0]) = pk;
    }
    // issue chunk 1 loads (converted at t=32)
#pragma unroll
    for (int j = 0; j < 4; ++j) xr[j] = ((const float4*)(xrbase + (size_t)CH * I_))[xl + 32 * j];

    float hreg[8];
#pragma unroll
    for (int s = 0; s < 8; ++s) hreg[s] = 0.f;

    const short* hrow = &h_lds[l15 * LSTR + quad * 8];

    for (int t = 0; t < T_; ++t) {
        const int tc  = t & (CH - 1);
        const int c   = t >> 6;
        const int buf = c & 1;

        __syncthreads();  // barrier #1: h_t (and any xstage writes) visible

        if (tc == 32) {  // convert held regs (chunk c+1) into idle buffer
#pragma unroll
            for (int j = 0; j < 4; ++j) {
                int e = j * 128 + xl * 4;
                int tl = e >> 3, i0 = e & 7;
                int2 pk = make_int2(pk2bf(xr[j].x, xr[j].y), pk2bf(xr[j].z, xr[j].w));
                *reinterpret_cast<int2*>(&xstage[buf ^ 1][tl][xrow][i0]) = pk;
            }
        }
        if (tc == 34) {  // issue loads for chunk c+2 (waited ~62 steps later)
            int cc = c + 2; if (cc > (T_ / CH) - 1) cc = (T_ / CH) - 1;
            const float4* src = (const float4*)(xrbase + (size_t)cc * CH * I_);
#pragma unroll
            for (int j = 0; j < 4; ++j) xr[j] = src[xl + 32 * j];
        }

        // ---- GEMM: 4 independent MFMA chains (dep depth 5/4) ----
        const short* xb = (quad == 0) ? &xstage[buf][tc][l15][0] : (const short*)zero16;
        f32x4 a0a, a0b, a1a, a1b;
#pragma unroll
        for (int r = 0; r < 4; ++r) {
            a0a[r] = p_bin[r]; a1a[r] = p_bin[4 + r];
            a0b[r] = 0.f;      a1b[r] = 0.f;
        }
        bf16x8 b8 = *reinterpret_cast<const bf16x8*>(xb);
#pragma unroll
        for (int ks = 0; ks < 4; ++ks) {
            bf16x8 bA = *reinterpret_cast<const bf16x8*>(hrow + ks * 32);
            bf16x8 bB = *reinterpret_cast<const bf16x8*>(hrow + (ks + 4) * 32);
            a0a = __builtin_amdgcn_mfma_f32_16x16x32_bf16(afrag[0][ks],     bA, a0a, 0, 0, 0);
            a1a = __builtin_amdgcn_mfma_f32_16x16x32_bf16(afrag[1][ks],     bA, a1a, 0, 0, 0);
            a0b = __builtin_amdgcn_mfma_f32_16x16x32_bf16(afrag[0][ks + 4], bB, a0b, 0, 0, 0);
            a1b = __builtin_amdgcn_mfma_f32_16x16x32_bf16(afrag[1][ks + 4], bB, a1b, 0, 0, 0);
        }
        a0a = __builtin_amdgcn_mfma_f32_16x16x32_bf16(afrag[0][8], b8, a0a, 0, 0, 0);
        a1a = __builtin_amdgcn_mfma_f32_16x16x32_bf16(afrag[1][8], b8, a1a, 0, 0, 0);
        f32x4 acc0 = a0a + a0b, acc1 = a1a + a1b;

        // ---- LN partial: in-lane fold + 2 shfl, write transposed ----
        float S  = ((acc0[0] + acc0[1]) + (acc0[2] + acc0[3]))
                 + ((acc1[0] + acc1[1]) + (acc1[2] + acc1[3]));
        float SQ = fmaf(acc0[0], acc0[0], fmaf(acc0[1], acc0[1],
                   fmaf(acc0[2], acc0[2], acc0[3] * acc0[3])))
                 + fmaf(acc1[0], acc1[0], fmaf(acc1[1], acc1[1],
                   fmaf(acc1[2], acc1[2], acc1[3] * acc1[3])));
        S += __shfl_xor(S, 16, 64);  SQ += __shfl_xor(SQ, 16, 64);
        S += __shfl_xor(S, 32, 64);  SQ += __shfl_xor(SQ, 32, 64);
        if (quad == 0) redt[l15][w] = make_float2(S, SQ);

        __syncthreads();  // barrier #2: all wave partials in redt

        // ---- final stats: 4x ds_read_b128 (all 8 partials) + add tree ----
        const float4* rrow = reinterpret_cast<const float4*>(&redt[l15][0]);
        float4 q0 = rrow[0], q1 = rrow[1], q2 = rrow[2], q3 = rrow[3];
        float St  = ((q0.x + q0.z) + (q1.x + q1.z)) + ((q2.x + q2.z) + (q3.x + q3.z));
        float SQt = ((q0.y + q0.w) + (q1.y + q1.w)) + ((q2.y + q2.w) + (q3.y + q3.w));
        const float mu   = St * (1.f / 256.f);
        const float var  = fmaf(SQt, 1.f / 256.f, -mu * mu);
        const float rstd = __builtin_amdgcn_rsqf(var + EPS_);
        const float nmr  = -mu * rstd;

        // ---- f = tanh(LN*g1+b1); h = clamp(h*decay + DT*f) ----
#pragma unroll
        for (int s = 0; s < 8; ++s) {
            float v  = (s < 4) ? acc0[s] : acc1[s - 4];
            float tt = fmaf(v, rstd, nmr);
            float z2 = fmaf(tt, p_g1s[s], p_b1s[s]);            // 2z/ln2
            float e  = __builtin_amdgcn_exp2f(z2);              // e^(2z)
            float rc = __builtin_amdgcn_rcpf(e + 1.f);
            float fd = fmaf(rc, -2.f * DT_, DT_);               // DT*tanh(z)
            float h  = fmaf(hreg[s], p_decay[s], fd);
            hreg[s]  = fminf(10.f, fmaxf(-10.f, h));
        }
        int2 pk0 = make_int2(pk2bf(hreg[0], hreg[1]), pk2bf(hreg[2], hreg[3]));
        int2 pk1 = make_int2(pk2bf(hreg[4], hreg[5]), pk2bf(hreg[6], hreg[7]));
        *reinterpret_cast<int2*>(&h_lds[l15 * LSTR + w * 32 + quad * 4])      = pk0;
        *reinterpret_cast<int2*>(&h_lds[l15 * LSTR + w * 32 + 16 + quad * 4]) = pk1;
    }

    // ---- epilogue: out = LN(h_T; g2,b2) @ head_w + head_b ----
    for (int i = tid; i < H_ * A_; i += 512) hw[i] = head_w[i];
    __syncthreads();

    float S2 = 0.f, SQ2 = 0.f;
#pragma unroll
    for (int s = 0; s < 8; ++s) { S2 += hreg[s]; SQ2 = fmaf(hreg[s], hreg[s], SQ2); }
    S2 += __shfl_xor(S2, 16, 64);  SQ2 += __shfl_xor(SQ2, 16, 64);
    S2 += __shfl_xor(S2, 32, 64);  SQ2 += __shfl_xor(SQ2, 32, 64);
    if (quad == 0) redep[w][l15] = make_float2(S2, SQ2);
    __syncthreads();
    float2 rA = redep[quad][l15], rB = redep[quad + 4][l15];
    float St = rA.x + rB.x, SQt = rA.y + rB.y;
    St += __shfl_xor(St, 16, 64);  SQt += __shfl_xor(SQt, 16, 64);
    St += __shfl_xor(St, 32, 64);  SQt += __shfl_xor(SQt, 32, 64);
    const float mu   = St * (1.f / 256.f);
    const float var  = fmaf(SQt, 1.f / 256.f, -mu * mu);
    const float rstd = __builtin_amdgcn_rsqf(var + EPS_);

    float pa[8];
#pragma unroll
    for (int a = 0; a < 8; ++a) pa[a] = 0.f;
#pragma unroll
    for (int s = 0; s < 8; ++s) {
        int c = w * 32 + (s >> 2) * 16 + quad * 4 + (s & 3);
        float lnh = (hreg[s] - mu) * rstd * g2[c] + beta2[c];
        float4 w0 = *reinterpret_cast<const float4*>(&hw[c * 8]);
        float4 w1 = *reinterpret_cast<const float4*>(&hw[c * 8 + 4]);
        pa[0] += lnh * w0.x; pa[1] += lnh * w0.y; pa[2] += lnh * w0.z; pa[3] += lnh * w0.w;
        pa[4] += lnh * w1.x; pa[5] += lnh * w1.y; pa[6] += lnh * w1.z; pa[7] += lnh * w1.w;
    }
#pragma unroll
    for (int a = 0; a < 8; ++a) {
        pa[a] += __shfl_xor(pa[a], 16, 64);
        pa[a] += __shfl_xor(pa[a], 32, 64);
    }
    if (quad == 0) {
#pragma unroll
        for (int a = 0; a < 8; ++a) outp[w][l15][a] = pa[a];
    }
    __syncthreads();
    if (tid < 128) {
        int r = tid >> 3, a = tid & 7;
        float s = head_b[a];
#pragma unroll
        for (int ww = 0; ww < 8; ++ww) s += outp[ww][r][a];
        out[(size_t)(r0 + r) * A_ + a] = s;
    }
}

extern "C" void kernel_launch(void* const* d_in, const int* in_sizes, int n_in,
                              void* d_out, int out_size, void* d_ws, size_t ws_size,
                              hipStream_t stream) {
    const float* x         = (const float*)d_in[0];
    const float* W_in      = (const float*)d_in[1];
    const float* b_in      = (const float*)d_in[2];
    const float* tau_param = (const float*)d_in[3];
    const float* W_rec     = (const float*)d_in[4];
    const float* g1        = (const float*)d_in[5];
    const float* beta1     = (const float*)d_in[6];
    const float* g2        = (const float*)d_in[7];
    const float* beta2     = (const float*)d_in[8];
    const float* head_w    = (const float*)d_in[9];
    const float* head_b    = (const float*)d_in[10];
    float* out = (float*)d_out;

    liquid_kernel<<<64, 512, 0, stream>>>(x, W_in, b_in, tau_param, W_rec,
                                          g1, beta1, g2, beta2, head_w, head_b, out);
}